// Round 1
// baseline (2184.237 us; speedup 1.0000x reference)
//
#include <hip/hip_runtime.h>
#include <math.h>

// Problem constants
#define NB 16      // batch
#define NN 4096    // n
#define DD 512     // d
#define K128 128   // k

// ---------------------------------------------------------------------------
// Kernel 1: projections  A[b] = evecs_x[b](128x4096) * feat_x[b](4096x512)
//           B[b] = evecs_y[b] * feat_y[b]
// Tile 64x128, BK=32, 256 threads, 8x4 micro-tile. grid (4,2,32).
// ---------------------------------------------------------------------------
__global__ __launch_bounds__(256) void gemm_proj_k(
    const float* __restrict__ feat_x, const float* __restrict__ feat_y,
    const float* __restrict__ evecs_x, const float* __restrict__ evecs_y,
    float* __restrict__ Aout, float* __restrict__ Bout)
{
    const int z = blockIdx.z;
    const int b = z & 15, which = z >> 4;
    const float* __restrict__ E = (which ? evecs_y : evecs_x) + (size_t)b * K128 * NN;
    const float* __restrict__ F = (which ? feat_y : feat_x) + (size_t)b * NN * DD;
    float* __restrict__ C = (which ? Bout : Aout) + (size_t)b * K128 * DD;
    const int i0 = blockIdx.y * 64;
    const int j0 = blockIdx.x * 128;

    __shared__ float As[32][68];    // transposed: As[k][i], +4 pad (16B-aligned rows)
    __shared__ float Bs[32][128];   // Bs[k][j]

    const int t  = threadIdx.x;
    const int tm = t >> 5;   // 0..7  -> 8 rows each
    const int tn = t & 31;   // 0..31 -> 4 cols each

    float acc[8][4];
#pragma unroll
    for (int r = 0; r < 8; ++r)
#pragma unroll
        for (int c = 0; c < 4; ++c) acc[r][c] = 0.f;

    for (int k0 = 0; k0 < NN; k0 += 32) {
        // stage E tile (64 rows x 32 k) transposed into As
#pragma unroll
        for (int s = 0; s < 2; ++s) {
            int idx = t + s * 256;          // 0..511 float4s
            int i = idx >> 3, kq = idx & 7;
            float4 v = *(const float4*)(E + (size_t)(i0 + i) * NN + k0 + kq * 4);
            As[kq * 4 + 0][i] = v.x; As[kq * 4 + 1][i] = v.y;
            As[kq * 4 + 2][i] = v.z; As[kq * 4 + 3][i] = v.w;
        }
        // stage F tile (32 k x 128 cols)
#pragma unroll
        for (int s = 0; s < 4; ++s) {
            int idx = t + s * 256;          // 0..1023 float4s
            int kk = idx >> 5, j4 = idx & 31;
            *(float4*)&Bs[kk][j4 * 4] =
                *(const float4*)(F + (size_t)(k0 + kk) * DD + j0 + j4 * 4);
        }
        __syncthreads();
#pragma unroll
        for (int kk = 0; kk < 32; ++kk) {
            float4 a0 = *(const float4*)&As[kk][tm * 8];
            float4 a1 = *(const float4*)&As[kk][tm * 8 + 4];
            float4 b0 = *(const float4*)&Bs[kk][tn * 4];
            float av[8] = {a0.x, a0.y, a0.z, a0.w, a1.x, a1.y, a1.z, a1.w};
            float bv[4] = {b0.x, b0.y, b0.z, b0.w};
#pragma unroll
            for (int r = 0; r < 8; ++r)
#pragma unroll
                for (int c = 0; c < 4; ++c)
                    acc[r][c] = fmaf(av[r], bv[c], acc[r][c]);
        }
        __syncthreads();
    }
#pragma unroll
    for (int r = 0; r < 8; ++r) {
        float4 v = make_float4(acc[r][0], acc[r][1], acc[r][2], acc[r][3]);
        *(float4*)(C + (size_t)(i0 + tm * 8 + r) * DD + j0 + tn * 4) = v;
    }
}

// ---------------------------------------------------------------------------
// Kernel 2: grams  C = X * Y^T, X,Y [128x512] row-major. 4 grams x 16 batches.
// Tile 64x64, 256 threads, 4x4 micro. grid (2,2,64).
// ---------------------------------------------------------------------------
__global__ __launch_bounds__(256) void gram_k(
    const float* __restrict__ A, const float* __restrict__ B,
    float* __restrict__ AAt, float* __restrict__ BBt,
    float* __restrict__ BAt, float* __restrict__ ABt)
{
    const int z = blockIdx.z;
    const int b = z & 15, g = z >> 4;
    const float* X; const float* Y; float* O;
    if (g == 0)      { X = A; Y = A; O = AAt; }
    else if (g == 1) { X = B; Y = B; O = BBt; }
    else if (g == 2) { X = B; Y = A; O = BAt; }   // BAt[i,j] = B_i . A_j
    else             { X = A; Y = B; O = ABt; }
    X += (size_t)b * K128 * DD; Y += (size_t)b * K128 * DD; O += (size_t)b * K128 * K128;
    const int i0 = blockIdx.y * 64, j0 = blockIdx.x * 64;

    __shared__ float Xs[32][68];
    __shared__ float Ys[32][68];

    const int t  = threadIdx.x;
    const int tm = t >> 4, tn = t & 15;   // 16x16 threads, 4x4 micro

    float acc[4][4];
#pragma unroll
    for (int r = 0; r < 4; ++r)
#pragma unroll
        for (int c = 0; c < 4; ++c) acc[r][c] = 0.f;

    for (int d0 = 0; d0 < DD; d0 += 32) {
#pragma unroll
        for (int s = 0; s < 2; ++s) {
            int idx = t + s * 256;     // 0..511 float4s (64 rows x 8 quads)
            int i = idx >> 3, kq = idx & 7;
            float4 v = *(const float4*)(X + (size_t)(i0 + i) * DD + d0 + kq * 4);
            Xs[kq * 4 + 0][i] = v.x; Xs[kq * 4 + 1][i] = v.y;
            Xs[kq * 4 + 2][i] = v.z; Xs[kq * 4 + 3][i] = v.w;
            float4 w = *(const float4*)(Y + (size_t)(j0 + i) * DD + d0 + kq * 4);
            Ys[kq * 4 + 0][i] = w.x; Ys[kq * 4 + 1][i] = w.y;
            Ys[kq * 4 + 2][i] = w.z; Ys[kq * 4 + 3][i] = w.w;
        }
        __syncthreads();
#pragma unroll
        for (int kk = 0; kk < 32; ++kk) {
            float4 a = *(const float4*)&Xs[kk][tm * 4];
            float4 bb = *(const float4*)&Ys[kk][tn * 4];
            float av[4] = {a.x, a.y, a.z, a.w};
            float bv[4] = {bb.x, bb.y, bb.z, bb.w};
#pragma unroll
            for (int r = 0; r < 4; ++r)
#pragma unroll
                for (int c = 0; c < 4; ++c)
                    acc[r][c] = fmaf(av[r], bv[c], acc[r][c]);
        }
        __syncthreads();
    }
#pragma unroll
    for (int r = 0; r < 4; ++r) {
        float4 v = make_float4(acc[r][0], acc[r][1], acc[r][2], acc[r][3]);
        *(float4*)(O + (size_t)(i0 + tm * 4 + r) * K128 + j0 + tn * 4) = v;
    }
}

// ---------------------------------------------------------------------------
// Kernel 3: D masks.  Dxy[b,i,j] = 100*M(ex->cols, ey->rows) + 25*M(aux).
// Dyx = Dxy^T (same pair scale). grid 16 blocks.
// ---------------------------------------------------------------------------
__global__ __launch_bounds__(256) void dmask_k(
    const float* __restrict__ evx, const float* __restrict__ evy,
    const float* __restrict__ avx, const float* __restrict__ avy,
    float* __restrict__ Dxy, float* __restrict__ Dyx)
{
    const int b = blockIdx.x;
    const int t = threadIdx.x;
    __shared__ float rx[128], sx[128], ry[128], sy[128];
    __shared__ float arx[128], asx[128], ary[128], asy[128];
    __shared__ float rm[4], ra[4];

    float ex = 0.f, ey = 0.f, ax = 0.f, ay = 0.f;
    if (t < 128) {
        ex = fmaxf(evx[b * 128 + t], 1e-10f);
        ey = fmaxf(evy[b * 128 + t], 1e-10f);
        ax = fmaxf(avx[b * 128 + t], 1e-10f);
        ay = fmaxf(avy[b * 128 + t], 1e-10f);
    }
    float lm = (t < 128) ? fmaxf(ex, ey) : 0.f;
    float la = (t < 128) ? fmaxf(ax, ay) : 0.f;
#pragma unroll
    for (int off = 32; off; off >>= 1) {
        lm = fmaxf(lm, __shfl_down(lm, off));
        la = fmaxf(la, __shfl_down(la, off));
    }
    if ((t & 63) == 0) { rm[t >> 6] = lm; ra[t >> 6] = la; }
    __syncthreads();
    const float sm = fmaxf(fmaxf(fmaxf(rm[0], rm[1]), fmaxf(rm[2], rm[3])), 1e-10f);
    const float sa = fmaxf(fmaxf(fmaxf(ra[0], ra[1]), fmaxf(ra[2], ra[3])), 1e-10f);

    if (t < 128) {
        float g, d;
        g = sqrtf(ex / sm); d = g * g + 1.f; rx[t] = g / d; sx[t] = 1.f / d;
        g = sqrtf(ey / sm); d = g * g + 1.f; ry[t] = g / d; sy[t] = 1.f / d;
        g = sqrtf(ax / sa); d = g * g + 1.f; arx[t] = g / d; asx[t] = 1.f / d;
        g = sqrtf(ay / sa); d = g * g + 1.f; ary[t] = g / d; asy[t] = 1.f / d;
    }
    __syncthreads();

    for (int idx = t; idx < 16384; idx += 256) {
        const int i = idx >> 7, j = idx & 127;   // row i from evals_y, col j from evals_x
        float mre = ry[i] - rx[j];
        float mim = sy[i] - sx[j];
        float m = mre * mre + mim * mim;
        float are_ = ary[i] - arx[j];
        float aim = asy[i] - asx[j];
        float ma = are_ * are_ + aim * aim;
        float dv = 100.f * m + 25.f * ma;
        Dxy[(size_t)b * 16384 + idx] = dv;
        Dyx[(size_t)b * 16384 + (size_t)j * 128 + i] = dv;
    }
}

// ---------------------------------------------------------------------------
// Kernel 4: Cholesky of K = G + reg*I (G = AAt for m<16 else BBt), then
// explicit inverse column-by-column (thread t = column). Kinv symmetric.
// grid 32 blocks x 256 threads. S is 64KB static LDS.
// ---------------------------------------------------------------------------
__global__ __launch_bounds__(256) void cholinv_k(
    const float* __restrict__ AAt, const float* __restrict__ BBt,
    float* __restrict__ Kinv)
{
    __shared__ float S[128][128];
    const int m = blockIdx.x;
    const float* __restrict__ G =
        (m < 16) ? (AAt + (size_t)m * 16384) : (BBt + (size_t)(m - 16) * 16384);
    float* __restrict__ KI = Kinv + (size_t)m * 16384;
    const int t = threadIdx.x;

    for (int idx = t; idx < 16384; idx += 256) {
        float v = G[idx];
        if ((idx >> 7) == (idx & 127)) v += 1e-6f;
        ((float*)S)[idx] = v;
    }
    __syncthreads();

    // Right-looking Cholesky (lower), full-square trailing update (keeps symmetry)
    for (int j = 0; j < 128; ++j) {
        float pj = sqrtf(S[j][j]);
        __syncthreads();
        if (t == 0) S[j][j] = pj;
        const float inv = 1.f / pj;
        for (int i = j + 1 + t; i < 128; i += 256) S[i][j] *= inv;
        __syncthreads();
        const int l = j + 1 + t;
        if (l < 128) {
            const float slj = S[l][j];
            for (int i = j + 1; i < 128; ++i) S[i][l] -= S[i][j] * slj;
        }
        __syncthreads();
    }

    // Per-column solve K x = e_j -> column j of Kinv (= row j by symmetry)
    if (t < 128) {
        const int j = t;
        float* __restrict__ row = KI + (size_t)j * 128;
        // forward: L z = e_j
        for (int i = 0; i < 128; ++i) {
            if (i < j) { row[i] = 0.f; continue; }
            float a = (i == j) ? 1.f : 0.f;
            for (int p = j; p < i; ++p) a -= S[i][p] * row[p];
            row[i] = a / S[i][i];
        }
        // backward: L^T x = z (in place)
        for (int i = 127; i >= 0; --i) {
            float a = row[i];
            for (int p = i + 1; p < 128; ++p) a -= S[p][i] * row[p];
            row[i] = a / S[i][i];
        }
    }
}

// ---------------------------------------------------------------------------
// Kernel 5: batched 128x128x128 GEMM for X0 / Richardson refinement.
// mode 0: Out = T_in * Kinv
// mode 1: Out = X0 - (Dm o T_in) * Kinv
// grid 32 (z = dir*16 + b), 256 threads, 8x8 micro.
// ---------------------------------------------------------------------------
__global__ __launch_bounds__(256) void solve_k(
    const float* __restrict__ T_in, const float* __restrict__ Dm,
    const float* __restrict__ X0, const float* __restrict__ Kinv,
    float* __restrict__ Out, const int mode)
{
    const int z = blockIdx.x;
    const size_t base = (size_t)z * 16384;

    __shared__ float Ts[32][132];   // transposed T: Ts[p][i]
    __shared__ float Ks[32][128];   // Ks[p][j]

    const int t  = threadIdx.x;
    const int tm = t >> 4, tn = t & 15;   // 16x16 threads, 8x8 micro

    float acc[8][8];
#pragma unroll
    for (int r = 0; r < 8; ++r)
#pragma unroll
        for (int c = 0; c < 8; ++c) acc[r][c] = 0.f;

    for (int p0 = 0; p0 < 128; p0 += 32) {
#pragma unroll
        for (int s = 0; s < 4; ++s) {
            int idx = t + s * 256;   // 0..1023 float4s (128 rows x 8 quads)
            int i = idx >> 3, pq = idx & 7;
            float4 v = *(const float4*)(T_in + base + (size_t)i * 128 + p0 + pq * 4);
            if (mode) {
                float4 dv = *(const float4*)(Dm + base + (size_t)i * 128 + p0 + pq * 4);
                v.x *= dv.x; v.y *= dv.y; v.z *= dv.z; v.w *= dv.w;
            }
            Ts[pq * 4 + 0][i] = v.x; Ts[pq * 4 + 1][i] = v.y;
            Ts[pq * 4 + 2][i] = v.z; Ts[pq * 4 + 3][i] = v.w;
        }
#pragma unroll
        for (int s = 0; s < 4; ++s) {
            int idx = t + s * 256;   // 0..1023 float4s (32 p-rows x 32 quads)
            int p = idx >> 5, j4 = idx & 31;
            *(float4*)&Ks[p][j4 * 4] =
                *(const float4*)(Kinv + base + (size_t)(p0 + p) * 128 + j4 * 4);
        }
        __syncthreads();
#pragma unroll
        for (int kk = 0; kk < 32; ++kk) {
            float4 a0 = *(const float4*)&Ts[kk][tm * 8];
            float4 a1 = *(const float4*)&Ts[kk][tm * 8 + 4];
            float4 b0 = *(const float4*)&Ks[kk][tn * 8];
            float4 b1 = *(const float4*)&Ks[kk][tn * 8 + 4];
            float av[8] = {a0.x, a0.y, a0.z, a0.w, a1.x, a1.y, a1.z, a1.w};
            float bv[8] = {b0.x, b0.y, b0.z, b0.w, b1.x, b1.y, b1.z, b1.w};
#pragma unroll
            for (int r = 0; r < 8; ++r)
#pragma unroll
                for (int c = 0; c < 8; ++c)
                    acc[r][c] = fmaf(av[r], bv[c], acc[r][c]);
        }
        __syncthreads();
    }

#pragma unroll
    for (int r = 0; r < 8; ++r) {
        const int i = tm * 8 + r;
#pragma unroll
        for (int cq = 0; cq < 2; ++cq) {
            float4 o = make_float4(acc[r][cq * 4 + 0], acc[r][cq * 4 + 1],
                                   acc[r][cq * 4 + 2], acc[r][cq * 4 + 3]);
            if (mode) {
                float4 x0v = *(const float4*)(X0 + base + (size_t)i * 128 + tn * 8 + cq * 4);
                o.x = x0v.x - o.x; o.y = x0v.y - o.y;
                o.z = x0v.z - o.z; o.w = x0v.w - o.w;
            }
            *(float4*)(Out + base + (size_t)i * 128 + tn * 8 + cq * 4) = o;
        }
    }
}

// ---------------------------------------------------------------------------
extern "C" void kernel_launch(void* const* d_in, const int* in_sizes, int n_in,
                              void* d_out, int out_size, void* d_ws, size_t ws_size,
                              hipStream_t stream)
{
    (void)in_sizes; (void)n_in; (void)out_size; (void)ws_size;
    const float* feat_x  = (const float*)d_in[0];
    const float* feat_y  = (const float*)d_in[1];
    const float* evals_x = (const float*)d_in[2];
    const float* evals_y = (const float*)d_in[3];
    const float* evecs_x = (const float*)d_in[4];
    const float* evecs_y = (const float*)d_in[5];
    const float* aux_x   = (const float*)d_in[6];
    const float* aux_y   = (const float*)d_in[7];
    float* out = (float*)d_out;
    float* ws  = (float*)d_ws;

    // workspace layout (floats)
    float* A    = ws;                 // 16*128*512   = 1048576
    float* B    = A    + 1048576;     // 1048576
    float* AAt  = B    + 1048576;     // 16*16384 = 262144
    float* BBt  = AAt  + 262144;
    float* R    = BBt  + 262144;      // 32*16384: [BAt(16) | ABt(16)]
    float* Dm   = R    + 524288;      // 32*16384: [Dxy | Dyx]
    float* Kinv = Dm   + 524288;      // 32*16384: [Kx | Ky]
    float* X0   = Kinv + 524288;      // 32*16384
    float* X1   = X0   + 524288;      // 32*16384   (total ~21 MB)

    gemm_proj_k<<<dim3(4, 2, 32), 256, 0, stream>>>(feat_x, feat_y, evecs_x, evecs_y, A, B);
    gram_k<<<dim3(2, 2, 64), 256, 0, stream>>>(A, B, AAt, BBt, R, R + 262144);
    dmask_k<<<16, 256, 0, stream>>>(evals_x, evals_y, aux_x, aux_y, Dm, Dm + 262144);
    cholinv_k<<<32, 256, 0, stream>>>(AAt, BBt, Kinv);
    // X0 = R * Kinv
    solve_k<<<32, 256, 0, stream>>>(R, nullptr, nullptr, Kinv, X0, 0);
    // X1 = X0 - (D o X0) * Kinv
    solve_k<<<32, 256, 0, stream>>>(X0, Dm, X0, Kinv, X1, 1);
    // Out = X0 - (D o X1) * Kinv   (writes d_out: [Cxy | Cyx])
    solve_k<<<32, 256, 0, stream>>>(X1, Dm, X0, Kinv, out, 1);
}

// Round 4
// 805.343 us; speedup vs baseline: 2.7122x; 2.7122x over previous
//
#include <hip/hip_runtime.h>
#include <math.h>

// Problem constants
#define NB 16      // batch
#define NN 4096    // n
#define DD 512     // d
#define K128 128   // k

// ---------------------------------------------------------------------------
// Kernel 1: projections  A[b] = evecs_x[b](128x4096) * feat_x[b](4096x512)
//           B[b] = evecs_y[b] * feat_y[b]
// Tile 64x128, BK=32, 256 threads, 8x4 micro-tile. grid (4,2,32).
// ---------------------------------------------------------------------------
__global__ __launch_bounds__(256) void gemm_proj_k(
    const float* __restrict__ feat_x, const float* __restrict__ feat_y,
    const float* __restrict__ evecs_x, const float* __restrict__ evecs_y,
    float* __restrict__ Aout, float* __restrict__ Bout)
{
    const int z = blockIdx.z;
    const int b = z & 15, which = z >> 4;
    const float* __restrict__ E = (which ? evecs_y : evecs_x) + (size_t)b * K128 * NN;
    const float* __restrict__ F = (which ? feat_y : feat_x) + (size_t)b * NN * DD;
    float* __restrict__ C = (which ? Bout : Aout) + (size_t)b * K128 * DD;
    const int i0 = blockIdx.y * 64;
    const int j0 = blockIdx.x * 128;

    __shared__ float As[32][68];    // transposed: As[k][i], +4 pad (16B-aligned rows)
    __shared__ float Bs[32][128];   // Bs[k][j]

    const int t  = threadIdx.x;
    const int tm = t >> 5;   // 0..7  -> 8 rows each
    const int tn = t & 31;   // 0..31 -> 4 cols each

    float acc[8][4];
#pragma unroll
    for (int r = 0; r < 8; ++r)
#pragma unroll
        for (int c = 0; c < 4; ++c) acc[r][c] = 0.f;

    for (int k0 = 0; k0 < NN; k0 += 32) {
        // stage E tile (64 rows x 32 k) transposed into As
#pragma unroll
        for (int s = 0; s < 2; ++s) {
            int idx = t + s * 256;          // 0..511 float4s
            int i = idx >> 3, kq = idx & 7;
            float4 v = *(const float4*)(E + (size_t)(i0 + i) * NN + k0 + kq * 4);
            As[kq * 4 + 0][i] = v.x; As[kq * 4 + 1][i] = v.y;
            As[kq * 4 + 2][i] = v.z; As[kq * 4 + 3][i] = v.w;
        }
        // stage F tile (32 k x 128 cols)
#pragma unroll
        for (int s = 0; s < 4; ++s) {
            int idx = t + s * 256;          // 0..1023 float4s
            int kk = idx >> 5, j4 = idx & 31;
            *(float4*)&Bs[kk][j4 * 4] =
                *(const float4*)(F + (size_t)(k0 + kk) * DD + j0 + j4 * 4);
        }
        __syncthreads();
#pragma unroll
        for (int kk = 0; kk < 32; ++kk) {
            float4 a0 = *(const float4*)&As[kk][tm * 8];
            float4 a1 = *(const float4*)&As[kk][tm * 8 + 4];
            float4 b0 = *(const float4*)&Bs[kk][tn * 4];
            float av[8] = {a0.x, a0.y, a0.z, a0.w, a1.x, a1.y, a1.z, a1.w};
            float bv[4] = {b0.x, b0.y, b0.z, b0.w};
#pragma unroll
            for (int r = 0; r < 8; ++r)
#pragma unroll
                for (int c = 0; c < 4; ++c)
                    acc[r][c] = fmaf(av[r], bv[c], acc[r][c]);
        }
        __syncthreads();
    }
#pragma unroll
    for (int r = 0; r < 8; ++r) {
        float4 v = make_float4(acc[r][0], acc[r][1], acc[r][2], acc[r][3]);
        *(float4*)(C + (size_t)(i0 + tm * 8 + r) * DD + j0 + tn * 4) = v;
    }
}

// ---------------------------------------------------------------------------
// Kernel 2: grams  C = X * Y^T, X,Y [128x512] row-major. 4 grams x 16 batches.
// Tile 64x64, 256 threads, 4x4 micro. grid (2,2,64).
// ---------------------------------------------------------------------------
__global__ __launch_bounds__(256) void gram_k(
    const float* __restrict__ A, const float* __restrict__ B,
    float* __restrict__ AAt, float* __restrict__ BBt,
    float* __restrict__ BAt, float* __restrict__ ABt)
{
    const int z = blockIdx.z;
    const int b = z & 15, g = z >> 4;
    const float* X; const float* Y; float* O;
    if (g == 0)      { X = A; Y = A; O = AAt; }
    else if (g == 1) { X = B; Y = B; O = BBt; }
    else if (g == 2) { X = B; Y = A; O = BAt; }   // BAt[i,j] = B_i . A_j
    else             { X = A; Y = B; O = ABt; }
    X += (size_t)b * K128 * DD; Y += (size_t)b * K128 * DD; O += (size_t)b * K128 * K128;
    const int i0 = blockIdx.y * 64, j0 = blockIdx.x * 64;

    __shared__ float Xs[32][68];
    __shared__ float Ys[32][68];

    const int t  = threadIdx.x;
    const int tm = t >> 4, tn = t & 15;   // 16x16 threads, 4x4 micro

    float acc[4][4];
#pragma unroll
    for (int r = 0; r < 4; ++r)
#pragma unroll
        for (int c = 0; c < 4; ++c) acc[r][c] = 0.f;

    for (int d0 = 0; d0 < DD; d0 += 32) {
#pragma unroll
        for (int s = 0; s < 2; ++s) {
            int idx = t + s * 256;     // 0..511 float4s (64 rows x 8 quads)
            int i = idx >> 3, kq = idx & 7;
            float4 v = *(const float4*)(X + (size_t)(i0 + i) * DD + d0 + kq * 4);
            Xs[kq * 4 + 0][i] = v.x; Xs[kq * 4 + 1][i] = v.y;
            Xs[kq * 4 + 2][i] = v.z; Xs[kq * 4 + 3][i] = v.w;
            float4 w = *(const float4*)(Y + (size_t)(j0 + i) * DD + d0 + kq * 4);
            Ys[kq * 4 + 0][i] = w.x; Ys[kq * 4 + 1][i] = w.y;
            Ys[kq * 4 + 2][i] = w.z; Ys[kq * 4 + 3][i] = w.w;
        }
        __syncthreads();
#pragma unroll
        for (int kk = 0; kk < 32; ++kk) {
            float4 a = *(const float4*)&Xs[kk][tm * 4];
            float4 bb = *(const float4*)&Ys[kk][tn * 4];
            float av[4] = {a.x, a.y, a.z, a.w};
            float bv[4] = {bb.x, bb.y, bb.z, bb.w};
#pragma unroll
            for (int r = 0; r < 4; ++r)
#pragma unroll
                for (int c = 0; c < 4; ++c)
                    acc[r][c] = fmaf(av[r], bv[c], acc[r][c]);
        }
        __syncthreads();
    }
#pragma unroll
    for (int r = 0; r < 4; ++r) {
        float4 v = make_float4(acc[r][0], acc[r][1], acc[r][2], acc[r][3]);
        *(float4*)(O + (size_t)(i0 + tm * 4 + r) * K128 + j0 + tn * 4) = v;
    }
}

// ---------------------------------------------------------------------------
// Kernel 3: D masks.  Dxy[b,i,j] = 100*M(ex->cols, ey->rows) + 25*M(aux).
// Dyx = Dxy^T (same pair scale). grid 16 blocks.
// ---------------------------------------------------------------------------
__global__ __launch_bounds__(256) void dmask_k(
    const float* __restrict__ evx, const float* __restrict__ evy,
    const float* __restrict__ avx, const float* __restrict__ avy,
    float* __restrict__ Dxy, float* __restrict__ Dyx)
{
    const int b = blockIdx.x;
    const int t = threadIdx.x;
    __shared__ float rx[128], sx[128], ry[128], sy[128];
    __shared__ float arx[128], asx[128], ary[128], asy[128];
    __shared__ float rm[4], ra[4];

    float ex = 0.f, ey = 0.f, ax = 0.f, ay = 0.f;
    if (t < 128) {
        ex = fmaxf(evx[b * 128 + t], 1e-10f);
        ey = fmaxf(evy[b * 128 + t], 1e-10f);
        ax = fmaxf(avx[b * 128 + t], 1e-10f);
        ay = fmaxf(avy[b * 128 + t], 1e-10f);
    }
    float lm = (t < 128) ? fmaxf(ex, ey) : 0.f;
    float la = (t < 128) ? fmaxf(ax, ay) : 0.f;
#pragma unroll
    for (int off = 32; off; off >>= 1) {
        lm = fmaxf(lm, __shfl_down(lm, off));
        la = fmaxf(la, __shfl_down(la, off));
    }
    if ((t & 63) == 0) { rm[t >> 6] = lm; ra[t >> 6] = la; }
    __syncthreads();
    const float sm = fmaxf(fmaxf(fmaxf(rm[0], rm[1]), fmaxf(rm[2], rm[3])), 1e-10f);
    const float sa = fmaxf(fmaxf(fmaxf(ra[0], ra[1]), fmaxf(ra[2], ra[3])), 1e-10f);

    if (t < 128) {
        float g, d;
        g = sqrtf(ex / sm); d = g * g + 1.f; rx[t] = g / d; sx[t] = 1.f / d;
        g = sqrtf(ey / sm); d = g * g + 1.f; ry[t] = g / d; sy[t] = 1.f / d;
        g = sqrtf(ax / sa); d = g * g + 1.f; arx[t] = g / d; asx[t] = 1.f / d;
        g = sqrtf(ay / sa); d = g * g + 1.f; ary[t] = g / d; asy[t] = 1.f / d;
    }
    __syncthreads();

    for (int idx = t; idx < 16384; idx += 256) {
        const int i = idx >> 7, j = idx & 127;   // row i from evals_y, col j from evals_x
        float mre = ry[i] - rx[j];
        float mim = sy[i] - sx[j];
        float m = mre * mre + mim * mim;
        float are_ = ary[i] - arx[j];
        float aim = asy[i] - asx[j];
        float ma = are_ * are_ + aim * aim;
        float dv = 100.f * m + 25.f * ma;
        Dxy[(size_t)b * 16384 + idx] = dv;
        Dyx[(size_t)b * 16384 + (size_t)j * 128 + i] = dv;
    }
}

// ---------------------------------------------------------------------------
// Kernel 4: in-place Gauss-Jordan inversion of K = G + reg*I in LDS.
// No pivoting (K is SPD, cond ~5-10). 128 pivot steps; each step is a
// fully-parallel rank-1 update (16384 FMAs over 512 threads, float4).
// grid 32 blocks x 512 threads, ~68.6KB LDS (rows padded to 132 floats
// to keep 16B alignment and break column-write bank conflicts).
// ---------------------------------------------------------------------------
__global__ __launch_bounds__(512) void gjinv_k(
    const float* __restrict__ AAt, const float* __restrict__ BBt,
    float* __restrict__ Kinv)
{
    __shared__ float S[128][132];
    __shared__ float rowj[128];
    __shared__ float colj[128];
    const int m = blockIdx.x;
    const float* __restrict__ G =
        (m < 16) ? (AAt + (size_t)m * 16384) : (BBt + (size_t)(m - 16) * 16384);
    float* __restrict__ KI = Kinv + (size_t)m * 16384;
    const int t = threadIdx.x;

    // load G + reg*I
    for (int idx = t; idx < 16384; idx += 512) {
        const int i = idx >> 7, c = idx & 127;
        S[i][c] = G[idx] + ((i == c) ? 1e-6f : 0.f);
    }
    __syncthreads();

    const int c4  = t & 31;    // float4 column quad (0..31)
    const int i00 = t >> 5;    // base row (0..15), stride 16, 8 rows/thread

    for (int j = 0; j < 128; ++j) {
        const float p = 1.f / S[j][j];
        if (t < 128) {
            rowj[t] = S[j][t] * p;
            colj[t] = (t == j) ? 0.f : S[t][j];
        }
        __syncthreads();

        // rank-1 update of the full matrix: S -= colj (x) rowj
        // (colj[j]=0 leaves row j unchanged; col j gets zeroed, fixed below)
        const float4 rv = *(const float4*)&rowj[c4 * 4];
#pragma unroll
        for (int s = 0; s < 8; ++s) {
            const int i = i00 + s * 16;
            const float cv = colj[i];
            float4 v = *(const float4*)&S[i][c4 * 4];
            v.x = fmaf(-cv, rv.x, v.x);
            v.y = fmaf(-cv, rv.y, v.y);
            v.z = fmaf(-cv, rv.z, v.z);
            v.w = fmaf(-cv, rv.w, v.w);
            *(float4*)&S[i][c4 * 4] = v;
        }
        __syncthreads();

        // fix pivot row / column / diagonal
        if (t < 128) {
            S[t][j] = (t == j) ? p : (-colj[t] * p);
            if (t != j) S[j][t] = rowj[t];
        }
        __syncthreads();
    }

    // write out the inverse
    for (int idx = t; idx < 16384; idx += 512) {
        const int i = idx >> 7, c = idx & 127;
        KI[idx] = S[i][c];
    }
}

// ---------------------------------------------------------------------------
// Kernel 5: batched 128x128x128 GEMM for X0 / Richardson refinement.
// mode 0: Out = T_in * Kinv
// mode 1: Out = X0 - (Dm o T_in) * Kinv
// grid 32 (z = dir*16 + b), 256 threads, 8x8 micro.
// ---------------------------------------------------------------------------
__global__ __launch_bounds__(256) void solve_k(
    const float* __restrict__ T_in, const float* __restrict__ Dm,
    const float* __restrict__ X0, const float* __restrict__ Kinv,
    float* __restrict__ Out, const int mode)
{
    const int z = blockIdx.x;
    const size_t base = (size_t)z * 16384;

    __shared__ float Ts[32][132];   // transposed T: Ts[p][i]
    __shared__ float Ks[32][128];   // Ks[p][j]

    const int t  = threadIdx.x;
    const int tm = t >> 4, tn = t & 15;   // 16x16 threads, 8x8 micro

    float acc[8][8];
#pragma unroll
    for (int r = 0; r < 8; ++r)
#pragma unroll
        for (int c = 0; c < 8; ++c) acc[r][c] = 0.f;

    for (int p0 = 0; p0 < 128; p0 += 32) {
#pragma unroll
        for (int s = 0; s < 4; ++s) {
            int idx = t + s * 256;   // 0..1023 float4s (128 rows x 8 quads)
            int i = idx >> 3, pq = idx & 7;
            float4 v = *(const float4*)(T_in + base + (size_t)i * 128 + p0 + pq * 4);
            if (mode) {
                float4 dv = *(const float4*)(Dm + base + (size_t)i * 128 + p0 + pq * 4);
                v.x *= dv.x; v.y *= dv.y; v.z *= dv.z; v.w *= dv.w;
            }
            Ts[pq * 4 + 0][i] = v.x; Ts[pq * 4 + 1][i] = v.y;
            Ts[pq * 4 + 2][i] = v.z; Ts[pq * 4 + 3][i] = v.w;
        }
#pragma unroll
        for (int s = 0; s < 4; ++s) {
            int idx = t + s * 256;   // 0..1023 float4s (32 p-rows x 32 quads)
            int p = idx >> 5, j4 = idx & 31;
            *(float4*)&Ks[p][j4 * 4] =
                *(const float4*)(Kinv + base + (size_t)(p0 + p) * 128 + j4 * 4);
        }
        __syncthreads();
#pragma unroll
        for (int kk = 0; kk < 32; ++kk) {
            float4 a0 = *(const float4*)&Ts[kk][tm * 8];
            float4 a1 = *(const float4*)&Ts[kk][tm * 8 + 4];
            float4 b0 = *(const float4*)&Ks[kk][tn * 8];
            float4 b1 = *(const float4*)&Ks[kk][tn * 8 + 4];
            float av[8] = {a0.x, a0.y, a0.z, a0.w, a1.x, a1.y, a1.z, a1.w};
            float bv[8] = {b0.x, b0.y, b0.z, b0.w, b1.x, b1.y, b1.z, b1.w};
#pragma unroll
            for (int r = 0; r < 8; ++r)
#pragma unroll
                for (int c = 0; c < 8; ++c)
                    acc[r][c] = fmaf(av[r], bv[c], acc[r][c]);
        }
        __syncthreads();
    }

#pragma unroll
    for (int r = 0; r < 8; ++r) {
        const int i = tm * 8 + r;
#pragma unroll
        for (int cq = 0; cq < 2; ++cq) {
            float4 o = make_float4(acc[r][cq * 4 + 0], acc[r][cq * 4 + 1],
                                   acc[r][cq * 4 + 2], acc[r][cq * 4 + 3]);
            if (mode) {
                float4 x0v = *(const float4*)(X0 + base + (size_t)i * 128 + tn * 8 + cq * 4);
                o.x = x0v.x - o.x; o.y = x0v.y - o.y;
                o.z = x0v.z - o.z; o.w = x0v.w - o.w;
            }
            *(float4*)(Out + base + (size_t)i * 128 + tn * 8 + cq * 4) = o;
        }
    }
}

// ---------------------------------------------------------------------------
extern "C" void kernel_launch(void* const* d_in, const int* in_sizes, int n_in,
                              void* d_out, int out_size, void* d_ws, size_t ws_size,
                              hipStream_t stream)
{
    (void)in_sizes; (void)n_in; (void)out_size; (void)ws_size;
    const float* feat_x  = (const float*)d_in[0];
    const float* feat_y  = (const float*)d_in[1];
    const float* evals_x = (const float*)d_in[2];
    const float* evals_y = (const float*)d_in[3];
    const float* evecs_x = (const float*)d_in[4];
    const float* evecs_y = (const float*)d_in[5];
    const float* aux_x   = (const float*)d_in[6];
    const float* aux_y   = (const float*)d_in[7];
    float* out = (float*)d_out;
    float* ws  = (float*)d_ws;

    // workspace layout (floats)
    float* A    = ws;                 // 16*128*512   = 1048576
    float* B    = A    + 1048576;     // 1048576
    float* AAt  = B    + 1048576;     // 16*16384 = 262144
    float* BBt  = AAt  + 262144;
    float* R    = BBt  + 262144;      // 32*16384: [BAt(16) | ABt(16)]
    float* Dm   = R    + 524288;      // 32*16384: [Dxy | Dyx]
    float* Kinv = Dm   + 524288;      // 32*16384: [Kx | Ky]
    float* X0   = Kinv + 524288;      // 32*16384
    float* X1   = X0   + 524288;      // 32*16384   (total ~21 MB)

    gemm_proj_k<<<dim3(4, 2, 32), 256, 0, stream>>>(feat_x, feat_y, evecs_x, evecs_y, A, B);
    gram_k<<<dim3(2, 2, 64), 256, 0, stream>>>(A, B, AAt, BBt, R, R + 262144);
    dmask_k<<<16, 256, 0, stream>>>(evals_x, evals_y, aux_x, aux_y, Dm, Dm + 262144);
    gjinv_k<<<32, 512, 0, stream>>>(AAt, BBt, Kinv);
    // X0 = R * Kinv
    solve_k<<<32, 256, 0, stream>>>(R, nullptr, nullptr, Kinv, X0, 0);
    // X1 = X0 - (D o X0) * Kinv
    solve_k<<<32, 256, 0, stream>>>(X0, Dm, X0, Kinv, X1, 1);
    // Out = X0 - (D o X1) * Kinv   (writes d_out: [Cxy | Cyx])
    solve_k<<<32, 256, 0, stream>>>(X1, Dm, X0, Kinv, out, 1);
}

// Round 5
// 648.969 us; speedup vs baseline: 3.3657x; 1.2410x over previous
//
#include <hip/hip_runtime.h>
#include <math.h>

// Problem constants
#define NB 16      // batch
#define NN 4096    // n
#define DD 512     // d
#define K128 128   // k
#define KSPLIT 2   // split-K factor for projection GEMM

typedef __attribute__((ext_vector_type(8))) short bf16x8;
typedef __attribute__((ext_vector_type(4))) float f32x4;

// split f32 -> bf16 hi (truncate) + bf16 lo (RNE of remainder)
__device__ __forceinline__ void split2(float x, unsigned short& h, unsigned short& l)
{
    unsigned u = __float_as_uint(x);
    h = (unsigned short)(u >> 16);
    float hf = __uint_as_float(u & 0xFFFF0000u);
    float r = x - hf;
    unsigned v = __float_as_uint(r);
    v += 0x7FFF + ((v >> 16) & 1);   // RNE
    l = (unsigned short)(v >> 16);
}

// ---------------------------------------------------------------------------
// Kernel 1: projections via bf16-split MFMA (3 products: hh + hl + lh).
// P[ks][z][128][512] partials; z = which*16 + b.  C = E(128x4096) * F(4096x512).
// Tile 128x128, BK=32, split-K=2 (K=2048/block). 512 threads = 8 waves (2x4),
// each wave computes 64x32 (4 m-frags x 2 n-frags).
// grid = nb(4) * pair(32) * ks(2) = 256 blocks.
// ---------------------------------------------------------------------------
__global__ __launch_bounds__(512) void proj_mfma_k(
    const float* __restrict__ feat_x, const float* __restrict__ feat_y,
    const float* __restrict__ evecs_x, const float* __restrict__ evecs_y,
    float* __restrict__ P)
{
    const int bx = blockIdx.x;
    const int nb = bx & 3;           // n-block (128 cols each)
    const int z  = (bx >> 2) & 31;   // pair
    const int ks = bx >> 7;          // k-split
    const int b = z & 15, which = z >> 4;
    const float* __restrict__ E = (which ? evecs_y : evecs_x) + (size_t)b * K128 * NN;
    const float* __restrict__ F = (which ? feat_y : feat_x) + (size_t)b * NN * DD;
    float* __restrict__ Po = P + ((size_t)ks * 32 + z) * (K128 * DD) + nb * 128;
    const int k_beg = ks * (NN / KSPLIT);

    __shared__ unsigned short Eh[128][40], El[128][40];   // E tile [m][k], pad->40
    __shared__ unsigned short Fh[128][40], Fl[128][40];   // F^T tile [n][k]

    const int t    = threadIdx.x;
    const int lane = t & 63;
    const int w    = t >> 6;              // wave 0..7
    const int wm   = (w >> 2) * 64;       // wave row offset (0,64)
    const int wn   = (w & 3) * 32;        // wave col offset (0,32,64,96)
    const int lr   = lane & 15;           // frag row/col
    const int lg   = lane >> 4;           // k-group 0..3

    f32x4 acc[4][2];
#pragma unroll
    for (int mi = 0; mi < 4; ++mi)
#pragma unroll
        for (int ni = 0; ni < 2; ++ni) acc[mi][ni] = (f32x4){0.f, 0.f, 0.f, 0.f};

    for (int k0 = 0; k0 < NN / KSPLIT; k0 += 32) {
        // stage E tile 128x32 (1024 float4 / 512 thr = 2 each)
#pragma unroll
        for (int s = 0; s < 2; ++s) {
            int idx = t + s * 512;
            int i = idx >> 3, kq = idx & 7;
            float4 v = *(const float4*)(E + (size_t)i * NN + k_beg + k0 + kq * 4);
            unsigned short h0, l0, h1, l1, h2, l2, h3, l3;
            split2(v.x, h0, l0); split2(v.y, h1, l1);
            split2(v.z, h2, l2); split2(v.w, h3, l3);
            *(ushort4*)&Eh[i][kq * 4] = make_ushort4(h0, h1, h2, h3);
            *(ushort4*)&El[i][kq * 4] = make_ushort4(l0, l1, l2, l3);
        }
        // stage F tile 32x128 transposed -> [n][k] (1024 float4 / 512 thr = 2)
#pragma unroll
        for (int s = 0; s < 2; ++s) {
            int idx = t + s * 512;
            int kk = idx >> 5, j4 = idx & 31;
            float4 v = *(const float4*)(F + (size_t)(k_beg + k0 + kk) * DD + nb * 128 + j4 * 4);
            unsigned short h0, l0, h1, l1, h2, l2, h3, l3;
            split2(v.x, h0, l0); split2(v.y, h1, l1);
            split2(v.z, h2, l2); split2(v.w, h3, l3);
            Fh[j4 * 4 + 0][kk] = h0; Fl[j4 * 4 + 0][kk] = l0;
            Fh[j4 * 4 + 1][kk] = h1; Fl[j4 * 4 + 1][kk] = l1;
            Fh[j4 * 4 + 2][kk] = h2; Fl[j4 * 4 + 2][kk] = l2;
            Fh[j4 * 4 + 3][kk] = h3; Fl[j4 * 4 + 3][kk] = l3;
        }
        __syncthreads();

        bf16x8 a_h[4], a_l[4];
#pragma unroll
        for (int mi = 0; mi < 4; ++mi) {
            a_h[mi] = *(const bf16x8*)&Eh[wm + mi * 16 + lr][lg * 8];
            a_l[mi] = *(const bf16x8*)&El[wm + mi * 16 + lr][lg * 8];
        }
#pragma unroll
        for (int ni = 0; ni < 2; ++ni) {
            bf16x8 b_h = *(const bf16x8*)&Fh[wn + ni * 16 + lr][lg * 8];
            bf16x8 b_l = *(const bf16x8*)&Fl[wn + ni * 16 + lr][lg * 8];
#pragma unroll
            for (int mi = 0; mi < 4; ++mi) {
                acc[mi][ni] = __builtin_amdgcn_mfma_f32_16x16x32_bf16(a_h[mi], b_h, acc[mi][ni], 0, 0, 0);
                acc[mi][ni] = __builtin_amdgcn_mfma_f32_16x16x32_bf16(a_h[mi], b_l, acc[mi][ni], 0, 0, 0);
                acc[mi][ni] = __builtin_amdgcn_mfma_f32_16x16x32_bf16(a_l[mi], b_h, acc[mi][ni], 0, 0, 0);
            }
        }
        __syncthreads();
    }

    // epilogue: D layout col=lane&15, row=(lane>>4)*4+reg
#pragma unroll
    for (int mi = 0; mi < 4; ++mi)
#pragma unroll
        for (int ni = 0; ni < 2; ++ni)
#pragma unroll
            for (int r = 0; r < 4; ++r) {
                const int row = wm + mi * 16 + lg * 4 + r;
                const int col = wn + ni * 16 + lr;
                Po[(size_t)row * DD + col] = acc[mi][ni][r];
            }
}

// ---------------------------------------------------------------------------
// Kernel 2: grams from split-K partials. X = P[0][z1]+P[1][z1], Y likewise.
// C = X * Y^T. Tile 64x64, 256 threads, 4x4 micro. grid (2,2,64).
// ---------------------------------------------------------------------------
__global__ __launch_bounds__(256) void gram_k(
    const float* __restrict__ P,
    float* __restrict__ AAt, float* __restrict__ BBt,
    float* __restrict__ BAt, float* __restrict__ ABt)
{
    const int zz = blockIdx.z;
    const int b = zz & 15, g = zz >> 4;
    int z1, z2; float* O;
    if (g == 0)      { z1 = b;      z2 = b;      O = AAt; }
    else if (g == 1) { z1 = 16 + b; z2 = 16 + b; O = BBt; }
    else if (g == 2) { z1 = 16 + b; z2 = b;      O = BAt; }   // BAt[i,j] = B_i . A_j
    else             { z1 = b;      z2 = 16 + b; O = ABt; }
    const float* __restrict__ Xp0 = P + (size_t)z1 * (K128 * DD);
    const float* __restrict__ Xp1 = Xp0 + (size_t)32 * K128 * DD;
    const float* __restrict__ Yp0 = P + (size_t)z2 * (K128 * DD);
    const float* __restrict__ Yp1 = Yp0 + (size_t)32 * K128 * DD;
    O += (size_t)b * K128 * K128;
    const int i0 = blockIdx.y * 64, j0 = blockIdx.x * 64;

    __shared__ float Xs[32][68];
    __shared__ float Ys[32][68];

    const int t  = threadIdx.x;
    const int tm = t >> 4, tn = t & 15;   // 16x16 threads, 4x4 micro

    float acc[4][4];
#pragma unroll
    for (int r = 0; r < 4; ++r)
#pragma unroll
        for (int c = 0; c < 4; ++c) acc[r][c] = 0.f;

    for (int d0 = 0; d0 < DD; d0 += 32) {
#pragma unroll
        for (int s = 0; s < 2; ++s) {
            int idx = t + s * 256;     // 0..511 float4s (64 rows x 8 quads)
            int i = idx >> 3, kq = idx & 7;
            size_t offX = (size_t)(i0 + i) * DD + d0 + kq * 4;
            float4 v = *(const float4*)(Xp0 + offX);
            float4 v1 = *(const float4*)(Xp1 + offX);
            v.x += v1.x; v.y += v1.y; v.z += v1.z; v.w += v1.w;
            Xs[kq * 4 + 0][i] = v.x; Xs[kq * 4 + 1][i] = v.y;
            Xs[kq * 4 + 2][i] = v.z; Xs[kq * 4 + 3][i] = v.w;
            size_t offY = (size_t)(j0 + i) * DD + d0 + kq * 4;
            float4 w = *(const float4*)(Yp0 + offY);
            float4 w1 = *(const float4*)(Yp1 + offY);
            w.x += w1.x; w.y += w1.y; w.z += w1.z; w.w += w1.w;
            Ys[kq * 4 + 0][i] = w.x; Ys[kq * 4 + 1][i] = w.y;
            Ys[kq * 4 + 2][i] = w.z; Ys[kq * 4 + 3][i] = w.w;
        }
        __syncthreads();
#pragma unroll
        for (int kk = 0; kk < 32; ++kk) {
            float4 a = *(const float4*)&Xs[kk][tm * 4];
            float4 bb = *(const float4*)&Ys[kk][tn * 4];
            float av[4] = {a.x, a.y, a.z, a.w};
            float bv[4] = {bb.x, bb.y, bb.z, bb.w};
#pragma unroll
            for (int r = 0; r < 4; ++r)
#pragma unroll
                for (int c = 0; c < 4; ++c)
                    acc[r][c] = fmaf(av[r], bv[c], acc[r][c]);
        }
        __syncthreads();
    }
#pragma unroll
    for (int r = 0; r < 4; ++r) {
        float4 v = make_float4(acc[r][0], acc[r][1], acc[r][2], acc[r][3]);
        *(float4*)(O + (size_t)(i0 + tm * 4 + r) * K128 + j0 + tn * 4) = v;
    }
}

// ---------------------------------------------------------------------------
// Kernel 3: D masks.  Dxy[b,i,j] = 100*M + 25*M_aux; Dyx = Dxy^T. grid 16.
// ---------------------------------------------------------------------------
__global__ __launch_bounds__(256) void dmask_k(
    const float* __restrict__ evx, const float* __restrict__ evy,
    const float* __restrict__ avx, const float* __restrict__ avy,
    float* __restrict__ Dxy, float* __restrict__ Dyx)
{
    const int b = blockIdx.x;
    const int t = threadIdx.x;
    __shared__ float rx[128], sx[128], ry[128], sy[128];
    __shared__ float arx[128], asx[128], ary[128], asy[128];
    __shared__ float rm[4], ra[4];

    float ex = 0.f, ey = 0.f, ax = 0.f, ay = 0.f;
    if (t < 128) {
        ex = fmaxf(evx[b * 128 + t], 1e-10f);
        ey = fmaxf(evy[b * 128 + t], 1e-10f);
        ax = fmaxf(avx[b * 128 + t], 1e-10f);
        ay = fmaxf(avy[b * 128 + t], 1e-10f);
    }
    float lm = (t < 128) ? fmaxf(ex, ey) : 0.f;
    float la = (t < 128) ? fmaxf(ax, ay) : 0.f;
#pragma unroll
    for (int off = 32; off; off >>= 1) {
        lm = fmaxf(lm, __shfl_down(lm, off));
        la = fmaxf(la, __shfl_down(la, off));
    }
    if ((t & 63) == 0) { rm[t >> 6] = lm; ra[t >> 6] = la; }
    __syncthreads();
    const float sm = fmaxf(fmaxf(fmaxf(rm[0], rm[1]), fmaxf(rm[2], rm[3])), 1e-10f);
    const float sa = fmaxf(fmaxf(fmaxf(ra[0], ra[1]), fmaxf(ra[2], ra[3])), 1e-10f);

    if (t < 128) {
        float g, d;
        g = sqrtf(ex / sm); d = g * g + 1.f; rx[t] = g / d; sx[t] = 1.f / d;
        g = sqrtf(ey / sm); d = g * g + 1.f; ry[t] = g / d; sy[t] = 1.f / d;
        g = sqrtf(ax / sa); d = g * g + 1.f; arx[t] = g / d; asx[t] = 1.f / d;
        g = sqrtf(ay / sa); d = g * g + 1.f; ary[t] = g / d; asy[t] = 1.f / d;
    }
    __syncthreads();

    for (int idx = t; idx < 16384; idx += 256) {
        const int i = idx >> 7, j = idx & 127;
        float mre = ry[i] - rx[j];
        float mim = sy[i] - sx[j];
        float m = mre * mre + mim * mim;
        float are_ = ary[i] - arx[j];
        float aim = asy[i] - asx[j];
        float ma = are_ * are_ + aim * aim;
        float dv = 100.f * m + 25.f * ma;
        Dxy[(size_t)b * 16384 + idx] = dv;
        Dyx[(size_t)b * 16384 + (size_t)j * 128 + i] = dv;
    }
}

// ---------------------------------------------------------------------------
// Kernel 4: in-place Gauss-Jordan inversion of K = G + reg*I in LDS.
// grid 32 blocks x 512 threads.
// ---------------------------------------------------------------------------
__global__ __launch_bounds__(512) void gjinv_k(
    const float* __restrict__ AAt, const float* __restrict__ BBt,
    float* __restrict__ Kinv)
{
    __shared__ float S[128][132];
    __shared__ float rowj[128];
    __shared__ float colj[128];
    const int m = blockIdx.x;
    const float* __restrict__ G =
        (m < 16) ? (AAt + (size_t)m * 16384) : (BBt + (size_t)(m - 16) * 16384);
    float* __restrict__ KI = Kinv + (size_t)m * 16384;
    const int t = threadIdx.x;

    for (int idx = t; idx < 16384; idx += 512) {
        const int i = idx >> 7, c = idx & 127;
        S[i][c] = G[idx] + ((i == c) ? 1e-6f : 0.f);
    }
    __syncthreads();

    const int c4  = t & 31;
    const int i00 = t >> 5;

    for (int j = 0; j < 128; ++j) {
        const float p = 1.f / S[j][j];
        if (t < 128) {
            rowj[t] = S[j][t] * p;
            colj[t] = (t == j) ? 0.f : S[t][j];
        }
        __syncthreads();

        const float4 rv = *(const float4*)&rowj[c4 * 4];
#pragma unroll
        for (int s = 0; s < 8; ++s) {
            const int i = i00 + s * 16;
            const float cv = colj[i];
            float4 v = *(const float4*)&S[i][c4 * 4];
            v.x = fmaf(-cv, rv.x, v.x);
            v.y = fmaf(-cv, rv.y, v.y);
            v.z = fmaf(-cv, rv.z, v.z);
            v.w = fmaf(-cv, rv.w, v.w);
            *(float4*)&S[i][c4 * 4] = v;
        }
        __syncthreads();

        if (t < 128) {
            S[t][j] = (t == j) ? p : (-colj[t] * p);
            if (t != j) S[j][t] = rowj[t];
        }
        __syncthreads();
    }

    for (int idx = t; idx < 16384; idx += 512) {
        const int i = idx >> 7, c = idx & 127;
        KI[idx] = S[i][c];
    }
}

// ---------------------------------------------------------------------------
// Kernel 5: batched 128x128x128 GEMM for X0 / Richardson refinement.
// mode 0: Out = T_in * Kinv ; mode 1: Out = X0 - (Dm o T_in) * Kinv
// grid 32, 256 threads, 8x8 micro.
// ---------------------------------------------------------------------------
__global__ __launch_bounds__(256) void solve_k(
    const float* __restrict__ T_in, const float* __restrict__ Dm,
    const float* __restrict__ X0, const float* __restrict__ Kinv,
    float* __restrict__ Out, const int mode)
{
    const int z = blockIdx.x;
    const size_t base = (size_t)z * 16384;

    __shared__ float Ts[32][132];
    __shared__ float Ks[32][128];

    const int t  = threadIdx.x;
    const int tm = t >> 4, tn = t & 15;

    float acc[8][8];
#pragma unroll
    for (int r = 0; r < 8; ++r)
#pragma unroll
        for (int c = 0; c < 8; ++c) acc[r][c] = 0.f;

    for (int p0 = 0; p0 < 128; p0 += 32) {
#pragma unroll
        for (int s = 0; s < 4; ++s) {
            int idx = t + s * 256;
            int i = idx >> 3, pq = idx & 7;
            float4 v = *(const float4*)(T_in + base + (size_t)i * 128 + p0 + pq * 4);
            if (mode) {
                float4 dv = *(const float4*)(Dm + base + (size_t)i * 128 + p0 + pq * 4);
                v.x *= dv.x; v.y *= dv.y; v.z *= dv.z; v.w *= dv.w;
            }
            Ts[pq * 4 + 0][i] = v.x; Ts[pq * 4 + 1][i] = v.y;
            Ts[pq * 4 + 2][i] = v.z; Ts[pq * 4 + 3][i] = v.w;
        }
#pragma unroll
        for (int s = 0; s < 4; ++s) {
            int idx = t + s * 256;
            int p = idx >> 5, j4 = idx & 31;
            *(float4*)&Ks[p][j4 * 4] =
                *(const float4*)(Kinv + base + (size_t)(p0 + p) * 128 + j4 * 4);
        }
        __syncthreads();
#pragma unroll
        for (int kk = 0; kk < 32; ++kk) {
            float4 a0 = *(const float4*)&Ts[kk][tm * 8];
            float4 a1 = *(const float4*)&Ts[kk][tm * 8 + 4];
            float4 b0 = *(const float4*)&Ks[kk][tn * 8];
            float4 b1 = *(const float4*)&Ks[kk][tn * 8 + 4];
            float av[8] = {a0.x, a0.y, a0.z, a0.w, a1.x, a1.y, a1.z, a1.w};
            float bv[8] = {b0.x, b0.y, b0.z, b0.w, b1.x, b1.y, b1.z, b1.w};
#pragma unroll
            for (int r = 0; r < 8; ++r)
#pragma unroll
                for (int c = 0; c < 8; ++c)
                    acc[r][c] = fmaf(av[r], bv[c], acc[r][c]);
        }
        __syncthreads();
    }

#pragma unroll
    for (int r = 0; r < 8; ++r) {
        const int i = tm * 8 + r;
#pragma unroll
        for (int cq = 0; cq < 2; ++cq) {
            float4 o = make_float4(acc[r][cq * 4 + 0], acc[r][cq * 4 + 1],
                                   acc[r][cq * 4 + 2], acc[r][cq * 4 + 3]);
            if (mode) {
                float4 x0v = *(const float4*)(X0 + base + (size_t)i * 128 + tn * 8 + cq * 4);
                o.x = x0v.x - o.x; o.y = x0v.y - o.y;
                o.z = x0v.z - o.z; o.w = x0v.w - o.w;
            }
            *(float4*)(Out + base + (size_t)i * 128 + tn * 8 + cq * 4) = o;
        }
    }
}

// ---------------------------------------------------------------------------
extern "C" void kernel_launch(void* const* d_in, const int* in_sizes, int n_in,
                              void* d_out, int out_size, void* d_ws, size_t ws_size,
                              hipStream_t stream)
{
    (void)in_sizes; (void)n_in; (void)out_size; (void)ws_size;
    const float* feat_x  = (const float*)d_in[0];
    const float* feat_y  = (const float*)d_in[1];
    const float* evals_x = (const float*)d_in[2];
    const float* evals_y = (const float*)d_in[3];
    const float* evecs_x = (const float*)d_in[4];
    const float* evecs_y = (const float*)d_in[5];
    const float* aux_x   = (const float*)d_in[6];
    const float* aux_y   = (const float*)d_in[7];
    float* out = (float*)d_out;
    float* ws  = (float*)d_ws;

    // workspace layout (floats), total 5,242,880 f32 = 21.0 MB (same as r1)
    // P (proj partials, KSPLIT*32*65536 = 4,194,304) is dead after gram_k;
    // Dm/Kinv/X0/X1 (2,097,152 total) alias into it afterwards.
    float* P    = ws;
    float* AAt  = ws + 4194304;       // 262144
    float* BBt  = AAt + 262144;       // 262144
    float* R    = BBt + 262144;       // 524288: [BAt(16) | ABt(16)]
    float* Dm   = ws;                 // alias (P dead after gram_k)
    float* Kinv = Dm + 524288;
    float* X0   = Kinv + 524288;
    float* X1   = X0 + 524288;

    proj_mfma_k<<<256, 512, 0, stream>>>(feat_x, feat_y, evecs_x, evecs_y, P);
    gram_k<<<dim3(2, 2, 64), 256, 0, stream>>>(P, AAt, BBt, R, R + 262144);
    dmask_k<<<16, 256, 0, stream>>>(evals_x, evals_y, aux_x, aux_y, Dm, Dm + 262144);
    gjinv_k<<<32, 512, 0, stream>>>(AAt, BBt, Kinv);
    // X0 = R * Kinv
    solve_k<<<32, 256, 0, stream>>>(R, nullptr, nullptr, Kinv, X0, 0);
    // X1 = X0 - (D o X0) * Kinv
    solve_k<<<32, 256, 0, stream>>>(X0, Dm, X0, Kinv, X1, 1);
    // Out = X0 - (D o X1) * Kinv   (writes d_out: [Cxy | Cyx])
    solve_k<<<32, 256, 0, stream>>>(X1, Dm, X0, Kinv, out, 1);
}